// Round 1
// baseline (498.562 us; speedup 1.0000x reference)
//
#include <hip/hip_runtime.h>
#include <math.h>

#define NB 16
#define NC 512
#define NK 128
#define SP 4096   // 64*64 spatial positions

// ---------------------------------------------------------------------------
// ws layout (floats):
//   [0      .. 2047 ]  SY   : sum over spatial of relu(wb*x+bb), per (b,k)
//   [2048   .. 4095 ]  SX1  : branch-1 sums
//   [4096   .. 6143 ]  SX2  : branch-2 sums
//   [6144   .. 22527]  sbr  : sigmoid outputs, 2 branches * 16 b * 512 c
//   [22528  .. 88063]  waT  : wa transposed to [c][k]
//   [88064  .. 153599] wbT  : wb transposed to [c][k]
// ---------------------------------------------------------------------------

__global__ __launch_bounds__(256) void transpose_w(
    const float* __restrict__ wa, const float* __restrict__ wb,
    float* __restrict__ waT, float* __restrict__ wbT) {
    int t = blockIdx.x * 256 + threadIdx.x;   // 0 .. 131071
    int src = t & 65535;
    int c = src >> 7, k = src & 127;
    if (t < 65536) waT[src] = wa[k * NC + c];
    else           wbT[src] = wb[k * NC + c];
}

// MODE 0: feaY conv (weights wbT, bias bb) on unpermuted x, positions = flat s.
// MODE 1: fX1 conv (weights waT, bias ba) on x1 view:
//         channel i at position (j,h) -> x[b, 64*(i&7)+j, i>>3, h]
// Block: (tile, b). tile = s-block (mode0) or j (mode1). 64 positions/block.
// Thread tile: 4 positions x 8 k. Accumulate full C=512 dot, relu+bias,
// sum over positions, atomicAdd into Ssum[b*K+k].
template <int MODE>
__global__ __launch_bounds__(256) void conv_mean(
    const float* __restrict__ x, const float* __restrict__ wT,
    const float* __restrict__ bias, float* __restrict__ Ssum) {
    __shared__ float xt[32 * 64];    // [c_local][pos]
    __shared__ float wt[32 * 128];   // [c_local][k]
    __shared__ float red[16 * 128];  // [pos_group][k]

    const int b = blockIdx.y;
    const int tile = blockIdx.x;
    const int t = threadIdx.x;
    const int pg = t >> 4;     // 16 position groups of 4
    const int kg = t & 15;     // 16 k groups of 8

    float acc[4][8];
#pragma unroll
    for (int p = 0; p < 4; ++p)
#pragma unroll
        for (int q = 0; q < 8; ++q) acc[p][q] = 0.f;

    for (int chunk = 0; chunk < 16; ++chunk) {
        const int c0 = chunk * 32;
        // stage x tile: 32 channels x 64 positions (coalesced in pos)
#pragma unroll
        for (int it = 0; it < 8; ++it) {
            int idx = it * 256 + t;
            int cl = idx >> 6, pos = idx & 63;
            int gaddr;
            if (MODE == 0) {
                gaddr = (b * NC + c0 + cl) * SP + tile * 64 + pos;
            } else {
                int i = c0 + cl;
                gaddr = (b * NC + 64 * (i & 7) + tile) * SP + (i >> 3) * 64 + pos;
            }
            xt[idx] = x[gaddr];
        }
        // stage weights: 32 c x 128 k from pre-transposed wT (coalesced)
#pragma unroll
        for (int it = 0; it < 16; ++it) {
            int idx = it * 256 + t;
            int cl = idx >> 7, k = idx & 127;
            wt[idx] = wT[(c0 + cl) * NK + k];
        }
        __syncthreads();
#pragma unroll 4
        for (int c = 0; c < 32; ++c) {
            float4 xv = *(const float4*)&xt[c * 64 + pg * 4];
            float4 w0 = *(const float4*)&wt[c * 128 + kg * 8];
            float4 w1 = *(const float4*)&wt[c * 128 + kg * 8 + 4];
            float xs[4] = {xv.x, xv.y, xv.z, xv.w};
            float wsv[8] = {w0.x, w0.y, w0.z, w0.w, w1.x, w1.y, w1.z, w1.w};
#pragma unroll
            for (int p = 0; p < 4; ++p)
#pragma unroll
                for (int q = 0; q < 8; ++q) acc[p][q] += xs[p] * wsv[q];
        }
        __syncthreads();
    }

    // relu(+bias) per position, sum over the thread's 4 positions
    float sp[8];
#pragma unroll
    for (int q = 0; q < 8; ++q) {
        float bv = bias[kg * 8 + q];
        float s = 0.f;
#pragma unroll
        for (int p = 0; p < 4; ++p) s += fmaxf(acc[p][q] + bv, 0.f);
        sp[q] = s;
    }
#pragma unroll
    for (int q = 0; q < 8; ++q) red[pg * 128 + kg * 8 + q] = sp[q];
    __syncthreads();
    if (t < 128) {
        float v = 0.f;
#pragma unroll
        for (int pgi = 0; pgi < 16; ++pgi) v += red[pgi * 128 + t];
        atomicAdd(&Ssum[b * NK + t], v);
    }
}

// Branch-2 conv: fX2[b,k,(j,l)] = relu(sum_i wa[k,i] * x[b,(j&7)*64+l,(i&7)*8+(j>>3), i>>3] + ba[k])
// For fixed (b, c_o = (j&7)*64+l) the 8 outputs j_hi = j>>3 together consume the
// whole 64x64 plane x[b,c_o,:,:]:
//   out[j_hi][k] = sum_{t8=0..7, a=0..63} wa[k, 8a+t8] * plane[8*t8+j_hi][a]
// Block per (c_o, b); plane staged transposed in LDS (pad 68 for aligned b128).
__global__ __launch_bounds__(256) void conv_mean_x2(
    const float* __restrict__ x, const float* __restrict__ waT,
    const float* __restrict__ bias, float* __restrict__ Ssum) {
    __shared__ float yt[64 * 68];   // yt[a][w] (transposed plane, padded)
    __shared__ float lw[64 * 128];  // weight chunk; reused as reduce buf [asub][jh][k]

    const int b = blockIdx.y;
    const int co = blockIdx.x;
    const int t = threadIdx.x;
    const int kg = t & 31;    // 32 k-groups of 4
    const int asub = t >> 5;  // 8-way split of 'a' within a chunk

    // stage plane, transposed: read x[b,co,w,a] coalesced in a, write yt[a][w]
#pragma unroll
    for (int it = 0; it < 16; ++it) {
        int idx = it * 256 + t;   // = w*64 + a
        int w = idx >> 6, a = idx & 63;
        yt[a * 68 + w] = x[(b * NC + co) * SP + idx];
    }

    float acc[8][4];
#pragma unroll
    for (int jh = 0; jh < 8; ++jh)
#pragma unroll
        for (int q = 0; q < 4; ++q) acc[jh][q] = 0.f;

    for (int ch = 0; ch < 8; ++ch) {
        const int i0 = ch * 64;
        __syncthreads();  // also makes plane visible before first compute
#pragma unroll
        for (int it = 0; it < 32; ++it) {
            int idx = it * 256 + t;   // 8192 = 64 i x 128 k
            int il = idx >> 7, k = idx & 127;
            lw[idx] = waT[(i0 + il) * NK + k];
        }
        __syncthreads();
        const int a = ch * 8 + asub;
#pragma unroll
        for (int t8 = 0; t8 < 8; ++t8) {
            float4 y0 = *(const float4*)&yt[a * 68 + t8 * 8];
            float4 y1 = *(const float4*)&yt[a * 68 + t8 * 8 + 4];
            float4 wv = *(const float4*)&lw[(8 * asub + t8) * 128 + kg * 4];
            float ys[8] = {y0.x, y0.y, y0.z, y0.w, y1.x, y1.y, y1.z, y1.w};
            float wsv[4] = {wv.x, wv.y, wv.z, wv.w};
#pragma unroll
            for (int jh = 0; jh < 8; ++jh)
#pragma unroll
                for (int q = 0; q < 4; ++q) acc[jh][q] += ys[jh] * wsv[q];
        }
    }

    __syncthreads();  // done reading lw as weights; reuse as reduce buffer
#pragma unroll
    for (int jh = 0; jh < 8; ++jh)
#pragma unroll
        for (int q = 0; q < 4; ++q)
            lw[asub * 1024 + jh * 128 + kg * 4 + q] = acc[jh][q];
    __syncthreads();
    if (t < 128) {
        float bv = bias[t];
        float val = 0.f;
#pragma unroll
        for (int jh = 0; jh < 8; ++jh) {
            float d = bv;
#pragma unroll
            for (int as = 0; as < 8; ++as) d += lw[as * 1024 + jh * 128 + t];
            val += fmaxf(d, 0.f);
        }
        atomicAdd(&Ssum[b * NK + t], val);
    }
}

// Per-(b,branch) MLP chain: ap = wd*(meanY+meanX); z = relu(wc1*ap+bc1);
// s = sigmoid(wc2*z+bc2). Writes sbr[branch][b][c].
__global__ __launch_bounds__(256) void chain_kernel(
    const float* __restrict__ Sy, const float* __restrict__ Sx1,
    const float* __restrict__ Sx2, const float* __restrict__ wd,
    const float* __restrict__ wc1, const float* __restrict__ bc1,
    const float* __restrict__ wc2, const float* __restrict__ bc2,
    float* __restrict__ sbr) {
    __shared__ float m[128];
    __shared__ float ap[512];
    __shared__ float z[128];
    const int b = blockIdx.x, br = blockIdx.y, t = threadIdx.x;
    const float* Sx = (br == 0) ? Sx1 : Sx2;
    const float inv = 1.0f / 4096.0f;

    if (t < 128) m[t] = (Sy[b * NK + t] + Sx[b * NK + t]) * inv;
    __syncthreads();
    for (int c = t; c < NC; c += 256) {
        float v = 0.f;
        for (int k = 0; k < NK; ++k) v += wd[c * NK + k] * m[k];
        ap[c] = v;
    }
    __syncthreads();
    if (t < 128) {
        float v = bc1[t];
        for (int c = 0; c < NC; ++c) v += wc1[t * NC + c] * ap[c];
        z[t] = fmaxf(v, 0.f);
    }
    __syncthreads();
    for (int c = t; c < NC; c += 256) {
        float v = bc2[c];
        for (int k = 0; k < NK; ++k) v += wc2[c * NK + k] * z[k];
        sbr[(br * NB + b) * NC + c] = 1.f / (1.f + expf(-v));
    }
}

// out[b,c,s] = x[b,c,s] + s1[b,c] + s2[b,c]
__global__ __launch_bounds__(256) void final_add(
    const float* __restrict__ x, const float* __restrict__ sbr,
    float* __restrict__ out) {
    const int total4 = NB * NC * SP / 4;   // 8388608
    for (int i = blockIdx.x * 256 + threadIdx.x; i < total4; i += gridDim.x * 256) {
        int flat = i * 4;
        int bc = flat >> 12;           // b*512 + c (4 | 4096, so uniform in float4)
        int b = bc >> 9, c = bc & 511;
        float s = sbr[b * NC + c] + sbr[NB * NC + b * NC + c];
        float4 xv = ((const float4*)x)[i];
        float4 o = {xv.x + s, xv.y + s, xv.z + s, xv.w + s};
        ((float4*)out)[i] = o;
    }
}

extern "C" void kernel_launch(void* const* d_in, const int* in_sizes, int n_in,
                              void* d_out, int out_size, void* d_ws, size_t ws_size,
                              hipStream_t stream) {
    const float* x   = (const float*)d_in[0];
    const float* wa  = (const float*)d_in[1];
    const float* ba  = (const float*)d_in[2];
    const float* wb  = (const float*)d_in[3];
    const float* bb  = (const float*)d_in[4];
    const float* wd  = (const float*)d_in[5];
    const float* wc1 = (const float*)d_in[6];
    const float* bc1 = (const float*)d_in[7];
    const float* wc2 = (const float*)d_in[8];
    const float* bc2 = (const float*)d_in[9];
    float* out = (float*)d_out;

    float* ws  = (float*)d_ws;
    float* SY  = ws;
    float* SX1 = ws + 2048;
    float* SX2 = ws + 4096;
    float* sbr = ws + 6144;
    float* waT = ws + 22528;
    float* wbT = ws + 88064;

    hipMemsetAsync(ws, 0, 6144 * sizeof(float), stream);
    transpose_w<<<512, 256, 0, stream>>>(wa, wb, waT, wbT);
    conv_mean<0><<<dim3(64, NB), 256, 0, stream>>>(x, wbT, bb, SY);
    conv_mean<1><<<dim3(64, NB), 256, 0, stream>>>(x, waT, ba, SX1);
    conv_mean_x2<<<dim3(NC, NB), 256, 0, stream>>>(x, waT, ba, SX2);
    chain_kernel<<<dim3(NB, 2), 256, 0, stream>>>(SY, SX1, SX2, wd, wc1, bc1, wc2, bc2, sbr);
    final_add<<<2048, 256, 0, stream>>>(x, sbr, out);
}

// Round 2
// 208.677 us; speedup vs baseline: 2.3892x; 2.3892x over previous
//
#include <hip/hip_runtime.h>
#include <math.h>

#define NB 16
#define NC 512
#define NK 128
#define SP 4096   // 64*64 spatial positions

typedef __attribute__((ext_vector_type(8))) short short8;
typedef __attribute__((ext_vector_type(4))) float f32x4;

__device__ inline unsigned short f2bf(float f) {
    unsigned int u = __builtin_bit_cast(unsigned int, f);
    u += 0x7fffu + ((u >> 16) & 1u);   // RNE
    return (unsigned short)(u >> 16);
}

// ---------------------------------------------------------------------------
// ws layout (float offsets):
//   [0    .. 2047 ]  SY    : sum over pos of relu(wb*x+bb), per (b,k)
//   [2048 .. 4095 ]  SX1
//   [4096 .. 6143 ]  SX2
//   [6144 .. 22527]  sbr   : sigmoid outputs, 2 br * 16 b * 512 c
//   [22528.. 55295]  w0bf  : bf16 wb[k][c]                  (65536 ushort)
//   [55296.. 88063]  w1bf  : bf16 wa[k][i'=64q+t]=wa[k][8t+q] (65536 ushort)
// ---------------------------------------------------------------------------

__global__ __launch_bounds__(256) void prep_weights(
    const float* __restrict__ wa, const float* __restrict__ wb,
    unsigned short* __restrict__ w0, unsigned short* __restrict__ w1) {
    int e = blockIdx.x * 256 + threadIdx.x;   // 0..65535
    w0[e] = f2bf(wb[e]);                      // same [k][c] layout
    int k = e >> 9, rem = e & 511, q = rem >> 6, t = rem & 63;
    w1[e] = f2bf(wa[k * 512 + 8 * t + q]);
}

// Canonical block GEMM: M=64 positions, N=128 k-out, K=512 (4 chunks of 128).
// VIEW 0: feaY on raw x      — block g = s-tile (64 flat positions)
// VIEW 1: fX1 on x1 view     — block g = j; positions = (j, h 0..63)
// VIEW 2: fX2 on x2 view     — block g = plane group (8 c); pos = (cl, jh)
// act[pos][i] staged in LDS bf16 with XOR swizzle; weights from pre-permuted
// bf16 arrays. acc += A*B per chunk; epilogue: relu(acc+bias), sum -> Ssum.
template <int VIEW>
__global__ __launch_bounds__(256) void conv_mfma(
    const float* __restrict__ x, const unsigned short* __restrict__ wbf,
    const float* __restrict__ bias, float* __restrict__ Ssum) {
    __shared__ __align__(16) unsigned short actS[64 * 128];   // 16 KB swizzled
    __shared__ __align__(16) unsigned short wS[128 * 128];    // 32 KB swizzled
    __shared__ float red[NK];

    const int b = blockIdx.y;
    const int g = blockIdx.x;
    const int t = threadIdx.x;
    const int wv = t >> 6;
    const int lane = t & 63;
    const int lr = lane & 15, lg = lane >> 4;

    if (t < NK) red[t] = 0.f;

    f32x4 acc[8];
#pragma unroll
    for (int n = 0; n < 8; ++n) acc[n] = (f32x4)(0.f);

    for (int ch = 0; ch < 4; ++ch) {
        // ---- stage weight chunk [128 k][128 i] bf16, swizzled ----
#pragma unroll
        for (int it = 0; it < 8; ++it) {
            int gi = it * 256 + t;            // 2048 granules of 16 B
            int k = gi >> 4, gg = gi & 15;
            uint4 v = *(const uint4*)(wbf + k * 512 + ch * 128 + gg * 8);
            *(uint4*)((char*)wS + k * 256 + ((gg ^ (k & 7)) << 4)) = v;
        }
        // ---- stage act chunk: 128 source rows of 64 floats, 1 row/wave-iter
#pragma unroll 4
        for (int r = wv; r < 128; r += 4) {
            int gaddr, pos, iloc;
            if (VIEW == 0) {
                int c = ch * 128 + r;
                gaddr = (b * NC + c) * SP + g * 64 + lane;
                pos = lane; iloc = r;
            } else if (VIEW == 1) {
                int qh = r >> 6, w = r & 63;
                int q = 2 * ch + qh;
                gaddr = (b * NC + 64 * q + g) * SP + w * 64 + lane;
                pos = lane; iloc = 64 * qh + w;
            } else {
                int cl = r >> 4, jh = (r >> 1) & 7, qh = r & 1;
                int q = 2 * ch + qh;
                gaddr = (b * NC + 8 * g + cl) * SP + (8 * q + jh) * 64 + lane;
                pos = cl * 8 + jh; iloc = 64 * qh + lane;
            }
            unsigned short v = f2bf(x[gaddr]);
            int byte = pos * 256 + ((((iloc >> 3) ^ (pos & 7)) << 4)) + (iloc & 7) * 2;
            *(unsigned short*)((char*)actS + byte) = v;
        }
        __syncthreads();
        // ---- MFMA: wave wv owns pos rows [wv*16, wv*16+16) ----
#pragma unroll
        for (int kk = 0; kk < 4; ++kk) {
            int prow = wv * 16 + lr;
            int ig = 4 * kk + lg;
            short8 a = *(const short8*)((const char*)actS + prow * 256 +
                                        ((ig ^ (prow & 7)) << 4));
#pragma unroll
            for (int n = 0; n < 8; ++n) {
                int krow = n * 16 + lr;
                short8 bf = *(const short8*)((const char*)wS + krow * 256 +
                                             ((ig ^ (krow & 7)) << 4));
                acc[n] = __builtin_amdgcn_mfma_f32_16x16x32_bf16(a, bf, acc[n], 0, 0, 0);
            }
        }
        __syncthreads();
    }

    // ---- epilogue: relu(dot+bias) summed over this block's 64 positions ----
#pragma unroll
    for (int n = 0; n < 8; ++n) {
        int k = n * 16 + lr;
        float bv = bias[k];
        float s = 0.f;
#pragma unroll
        for (int rr = 0; rr < 4; ++rr) s += fmaxf(acc[n][rr] + bv, 0.f);
        atomicAdd(&red[k], s);
    }
    __syncthreads();
    if (t < NK) atomicAdd(&Ssum[b * NK + t], red[t]);
}

// Per-(b,branch) MLP chain: ap = wd*(meanY+meanX); z = relu(wc1*ap+bc1);
// s = sigmoid(wc2*z+bc2). Writes sbr[branch][b][c].
__global__ __launch_bounds__(256) void chain_kernel(
    const float* __restrict__ Sy, const float* __restrict__ Sx1,
    const float* __restrict__ Sx2, const float* __restrict__ wd,
    const float* __restrict__ wc1, const float* __restrict__ bc1,
    const float* __restrict__ wc2, const float* __restrict__ bc2,
    float* __restrict__ sbr) {
    __shared__ float m[128];
    __shared__ float ap[512];
    __shared__ float z[128];
    const int b = blockIdx.x, br = blockIdx.y, t = threadIdx.x;
    const float* Sx = (br == 0) ? Sx1 : Sx2;
    const float inv = 1.0f / 4096.0f;

    if (t < 128) m[t] = (Sy[b * NK + t] + Sx[b * NK + t]) * inv;
    __syncthreads();
    for (int c = t; c < NC; c += 256) {
        float v = 0.f;
        for (int k = 0; k < NK; ++k) v += wd[c * NK + k] * m[k];
        ap[c] = v;
    }
    __syncthreads();
    if (t < 128) {
        float v = bc1[t];
        for (int c = 0; c < NC; ++c) v += wc1[t * NC + c] * ap[c];
        z[t] = fmaxf(v, 0.f);
    }
    __syncthreads();
    for (int c = t; c < NC; c += 256) {
        float v = bc2[c];
        for (int k = 0; k < NK; ++k) v += wc2[c * NK + k] * z[k];
        sbr[(br * NB + b) * NC + c] = 1.f / (1.f + expf(-v));
    }
}

// out[b,c,s] = x[b,c,s] + s1[b,c] + s2[b,c]
__global__ __launch_bounds__(256) void final_add(
    const float* __restrict__ x, const float* __restrict__ sbr,
    float* __restrict__ out) {
    const int total4 = NB * NC * SP / 4;   // 8388608
    for (int i = blockIdx.x * 256 + threadIdx.x; i < total4; i += gridDim.x * 256) {
        int flat = i * 4;
        int bc = flat >> 12;
        int b = bc >> 9, c = bc & 511;
        float s = sbr[b * NC + c] + sbr[NB * NC + b * NC + c];
        float4 xv = ((const float4*)x)[i];
        float4 o = {xv.x + s, xv.y + s, xv.z + s, xv.w + s};
        ((float4*)out)[i] = o;
    }
}

extern "C" void kernel_launch(void* const* d_in, const int* in_sizes, int n_in,
                              void* d_out, int out_size, void* d_ws, size_t ws_size,
                              hipStream_t stream) {
    const float* x   = (const float*)d_in[0];
    const float* wa  = (const float*)d_in[1];
    const float* ba  = (const float*)d_in[2];
    const float* wb  = (const float*)d_in[3];
    const float* bb  = (const float*)d_in[4];
    const float* wd  = (const float*)d_in[5];
    const float* wc1 = (const float*)d_in[6];
    const float* bc1 = (const float*)d_in[7];
    const float* wc2 = (const float*)d_in[8];
    const float* bc2 = (const float*)d_in[9];
    float* out = (float*)d_out;

    float* ws  = (float*)d_ws;
    float* SY  = ws;
    float* SX1 = ws + 2048;
    float* SX2 = ws + 4096;
    float* sbr = ws + 6144;
    unsigned short* w0bf = (unsigned short*)(ws + 22528);
    unsigned short* w1bf = (unsigned short*)(ws + 55296);

    hipMemsetAsync(ws, 0, 6144 * sizeof(float), stream);
    prep_weights<<<256, 256, 0, stream>>>(wa, wb, w0bf, w1bf);
    conv_mfma<0><<<dim3(64, NB), 256, 0, stream>>>(x, w0bf, bb, SY);
    conv_mfma<1><<<dim3(64, NB), 256, 0, stream>>>(x, w1bf, ba, SX1);
    conv_mfma<2><<<dim3(64, NB), 256, 0, stream>>>(x, w1bf, ba, SX2);
    chain_kernel<<<dim3(NB, 2), 256, 0, stream>>>(SY, SX1, SX2, wd, wc1, bc1, wc2, bc2, sbr);
    final_add<<<2048, 256, 0, stream>>>(x, sbr, out);
}